// Round 2
// baseline (528.308 us; speedup 1.0000x reference)
//
#include <hip/hip_runtime.h>

#define N_NODES 100000
#define N_EDGES 1600000
#define IN_CH   64
#define HID_CH  64
#define OUT_CH  128
#define TILE    128
#define N_TILES (N_EDGES / TILE)   // 12500 exactly

typedef __attribute__((ext_vector_type(8))) __bf16 bf16x8;
typedef __attribute__((ext_vector_type(4))) float  f32x4;

__device__ __forceinline__ unsigned short f2bf(float f) {
    union { float f; unsigned int i; } c;
    c.f = f;
    unsigned int u = c.i;
    unsigned int r = (u + 0x7FFFu + ((u >> 16) & 1u)) >> 16;   // RNE
    return (unsigned short)r;
}

// fp32 x[N_NODES][64] -> bf16 bits in ws (so edge gather is 16B/lane bf16)
__global__ void x_to_bf16(const float* __restrict__ xf,
                          unsigned short* __restrict__ xb) {
    int i = blockIdx.x * blockDim.x + threadIdx.x;   // vec4 index, exact fit
    float4 v = reinterpret_cast<const float4*>(xf)[i];
    ushort4 o;
    o.x = f2bf(v.x); o.y = f2bf(v.y); o.z = f2bf(v.z); o.w = f2bf(v.w);
    reinterpret_cast<ushort4*>(xb)[i] = o;
}

// One workgroup = 256 threads = 4 waves; each wave owns 32 edges of a
// 128-edge tile. Layer1: M=32,N=64,K=128 MFMA ([x_dst|x_src] bf16 gathered
// from ws), edge_attr (fp32) + b1 folded into accumulator init on VALU.
// Layer2: M=32,N=128,K=64 via per-wave LDS round-trip of relu'd hidden.
// Epilogue: (acc + b2) masked -> fp32 atomicAdd into out[dst] (pre-zeroed).
__global__ __launch_bounds__(256, 2) void gnn_edge_mlp(
    const float*          __restrict__ x,     // [N_NODES][64] fp32 (node type)
    const unsigned short* __restrict__ xb,    // [N_NODES][64] bf16 bits (ws)
    const int*            __restrict__ eidx,  // [2][N_EDGES]
    const float*          __restrict__ ea,    // [N_EDGES][3]
    const float*          __restrict__ W1,    // [131][64]
    const float*          __restrict__ b1,    // [64]
    const float*          __restrict__ W2,    // [64][128]
    const float*          __restrict__ b2,    // [128]
    float*                __restrict__ out)   // [N_NODES][128] fp32 accum
{
    // +8-short row padding keeps ds_read_b128 bank-balanced
    __shared__ __align__(16) unsigned short W1T[64][136];   // W1T[n][k]=W1[k][n], k<128
    __shared__ __align__(16) unsigned short W2T[128][72];   // W2T[n][k]=W2[k][n]
    __shared__ __align__(16) unsigned short H2[4][32][72];  // per-wave hidden (bf16)
    __shared__ float w1tail[4][64];   // W1[128],W1[129],W1[130], b1 (fp32)
    __shared__ float b2s[128];
    __shared__ float eas[128][4];
    __shared__ float masks[128];
    __shared__ int   dsts[128];
    __shared__ int   srcs[128];

    const int tid  = threadIdx.x;
    const int wave = tid >> 6;
    const int lane = tid & 63;
    const int q    = lane >> 4;   // quad 0..3
    const int m16  = lane & 15;

    // ---- stage weights once per persistent block (fp32 -> bf16) ----
    for (int idx = tid; idx < 128 * 64; idx += 256) {
        int k = idx >> 6, n = idx & 63;
        W1T[n][k] = f2bf(W1[idx]);
    }
    for (int idx = tid; idx < 64 * 128; idx += 256) {
        int k = idx >> 7, n = idx & 127;
        W2T[n][k] = f2bf(W2[idx]);
    }
    if (tid < 64) {
        w1tail[0][tid] = W1[128 * 64 + tid];
        w1tail[1][tid] = W1[129 * 64 + tid];
        w1tail[2][tid] = W1[130 * 64 + tid];
        w1tail[3][tid] = b1[tid];
    }
    if (tid < 128) b2s[tid] = b2[tid];

    for (int t = blockIdx.x; t < N_TILES; t += gridDim.x) {
        __syncthreads();   // covers weight staging (1st iter) + LDS WAR reuse
        if (tid < 128) {
            int e = t * TILE + tid;
            int s = eidx[e];
            int d = eidx[N_EDGES + e];
            srcs[tid] = s;
            dsts[tid] = d;
            float a0 = ea[e * 3 + 0];
            float a1 = ea[e * 3 + 1];
            float a2 = ea[e * 3 + 2];
            eas[tid][0] = a0; eas[tid][1] = a1; eas[tid][2] = a2;
            float nt = x[(size_t)s * IN_CH];   // node type of source (exact)
            float mk;
            if (nt == 0.0f)      mk = (a0 < 0.5f) ? 1.0f : 0.0f;
            else if (nt == 1.0f) mk = (a0 < 0.3f) ? 1.0f : 0.0f;
            else                 mk = 1.0f;
            masks[tid] = mk;
        }
        __syncthreads();

        const int ebase = wave * 32;

        // ---- layer 1: init acc with b1 + ea @ W1[128:131] (fp32 VALU) ----
        f32x4 acc1[2][4];
#pragma unroll
        for (int mt = 0; mt < 2; ++mt) {
            float e0[4], e1[4], e2[4];
#pragma unroll
            for (int r = 0; r < 4; ++r) {
                int el = ebase + mt * 16 + q * 4 + r;   // C-layout row
                e0[r] = eas[el][0]; e1[r] = eas[el][1]; e2[r] = eas[el][2];
            }
#pragma unroll
            for (int nt = 0; nt < 4; ++nt) {
                int n = nt * 16 + m16;                  // C-layout col
                float t0 = w1tail[0][n], t1 = w1tail[1][n];
                float t2 = w1tail[2][n], bb = w1tail[3][n];
#pragma unroll
                for (int r = 0; r < 4; ++r)
                    acc1[mt][nt][r] = bb + e0[r] * t0 + e1[r] * t1 + e2[r] * t2;
            }
        }

        // K=128 over [x_dst (kc 0,1) | x_src (kc 2,3)], A-frags from global bf16
#pragma unroll
        for (int kc = 0; kc < 4; ++kc) {
            bf16x8 af[2];
#pragma unroll
            for (int mt = 0; mt < 2; ++mt) {
                int el   = ebase + mt * 16 + m16;       // A-layout row m=lane&15
                int node = (kc < 2) ? dsts[el] : srcs[el];
                af[mt] = *reinterpret_cast<const bf16x8*>(
                    xb + (size_t)node * IN_CH + (kc & 1) * 32 + q * 8);
            }
#pragma unroll
            for (int nt = 0; nt < 4; ++nt) {
                bf16x8 bfr = *reinterpret_cast<const bf16x8*>(
                    &W1T[nt * 16 + m16][kc * 32 + q * 8]);
                acc1[0][nt] = __builtin_amdgcn_mfma_f32_16x16x32_bf16(af[0], bfr, acc1[0][nt], 0, 0, 0);
                acc1[1][nt] = __builtin_amdgcn_mfma_f32_16x16x32_bf16(af[1], bfr, acc1[1][nt], 0, 0, 0);
            }
        }

        // relu -> per-wave LDS (C-layout -> A-layout round trip; same-wave,
        // no barrier needed — lgkmcnt ordering suffices)
#pragma unroll
        for (int mt = 0; mt < 2; ++mt)
#pragma unroll
            for (int nt = 0; nt < 4; ++nt)
#pragma unroll
                for (int r = 0; r < 4; ++r) {
                    float v = acc1[mt][nt][r];
                    v = v > 0.0f ? v : 0.0f;
                    H2[wave][mt * 16 + q * 4 + r][nt * 16 + m16] = f2bf(v);
                }

        // ---- layer 2: M=32, N=128, K=64 ----
        f32x4 acc2[2][8];
#pragma unroll
        for (int mt = 0; mt < 2; ++mt)
#pragma unroll
            for (int nt = 0; nt < 8; ++nt)
                acc2[mt][nt] = (f32x4){0.0f, 0.0f, 0.0f, 0.0f};

#pragma unroll
        for (int kc = 0; kc < 2; ++kc) {
            bf16x8 af[2];
#pragma unroll
            for (int mt = 0; mt < 2; ++mt)
                af[mt] = *reinterpret_cast<const bf16x8*>(
                    &H2[wave][mt * 16 + m16][kc * 32 + q * 8]);
#pragma unroll
            for (int nt = 0; nt < 8; ++nt) {
                bf16x8 bfr = *reinterpret_cast<const bf16x8*>(
                    &W2T[nt * 16 + m16][kc * 32 + q * 8]);
                acc2[0][nt] = __builtin_amdgcn_mfma_f32_16x16x32_bf16(af[0], bfr, acc2[0][nt], 0, 0, 0);
                acc2[1][nt] = __builtin_amdgcn_mfma_f32_16x16x32_bf16(af[1], bfr, acc2[1][nt], 0, 0, 0);
            }
        }

        // ---- epilogue: (acc + b2) masked -> fp32 atomic scatter-add ----
#pragma unroll
        for (int mt = 0; mt < 2; ++mt) {
            float mk[4]; int dd[4];
#pragma unroll
            for (int r = 0; r < 4; ++r) {
                int el = ebase + mt * 16 + q * 4 + r;
                mk[r] = masks[el];
                dd[r] = dsts[el];
            }
#pragma unroll
            for (int nt = 0; nt < 8; ++nt) {
                int col = nt * 16 + m16;
                float bb = b2s[col];
#pragma unroll
                for (int r = 0; r < 4; ++r) {
                    if (mk[r] != 0.0f) {
                        float v = acc2[mt][nt][r] + bb;
                        unsafeAtomicAdd(&out[(size_t)dd[r] * OUT_CH + col], v);
                    }
                }
            }
        }
    }
}

// in-place relu on the fp32 accumulator (= d_out)
__global__ void gnn_finalize(float* __restrict__ out) {
    size_t i = (size_t)blockIdx.x * blockDim.x + threadIdx.x;   // vec4 index
    f32x4 v = reinterpret_cast<const f32x4*>(out)[i];
    v.x = v.x > 0.0f ? v.x : 0.0f;
    v.y = v.y > 0.0f ? v.y : 0.0f;
    v.z = v.z > 0.0f ? v.z : 0.0f;
    v.w = v.w > 0.0f ? v.w : 0.0f;
    reinterpret_cast<f32x4*>(out)[i] = v;
}

extern "C" void kernel_launch(void* const* d_in, const int* in_sizes, int n_in,
                              void* d_out, int out_size, void* d_ws, size_t ws_size,
                              hipStream_t stream) {
    const float* x  = (const float*)d_in[0];
    const int*   ei = (const int*)d_in[1];
    const float* ea = (const float*)d_in[2];
    const float* W1 = (const float*)d_in[3];
    const float* b1 = (const float*)d_in[4];
    const float* W2 = (const float*)d_in[5];
    const float* b2 = (const float*)d_in[6];
    float* out = (float*)d_out;
    unsigned short* xb = (unsigned short*)d_ws;   // 12.8 MB bf16 x

    // d_out doubles as the fp32 segment-sum accumulator (re-poisoned each call)
    hipMemsetAsync(out, 0, (size_t)N_NODES * OUT_CH * sizeof(float), stream);

    // fp32 -> bf16 conversion of x (6.4M elems, vec4, exact fit)
    x_to_bf16<<<(N_NODES * IN_CH) / 4 / 256, 256, 0, stream>>>(x, xb);

    // 512 persistent blocks = 2 blocks/CU (LDS-limited), weights staged once
    gnn_edge_mlp<<<512, 256, 0, stream>>>(x, xb, ei, ea, W1, b1, W2, b2, out);

    // in-place relu (12.8M floats, vec4, exact fit)
    gnn_finalize<<<(N_NODES * OUT_CH) / 4 / 256, 256, 0, stream>>>(out);
}